// Round 1
// baseline (1332.030 us; speedup 1.0000x reference)
//
#include <hip/hip_runtime.h>

#define BB 4
#define NT 256
#define NZ 384
#define NX 384
#define NREC 128
#define NZX (NZ*NX)        // 147456
#define BNZX (BB*NZX)      // 589824
#define DT 0.001f
#define INV_DH2 0.01f      // 1/(10*10)

// Zero the two ping-pong wavefield buffers, precompute c2dt2 = (vp*DT)^2.
__global__ void wave_init(const float* __restrict__ vp, float* __restrict__ hA,
                          float* __restrict__ hB, float* __restrict__ c2) {
    int idx = blockIdx.x * blockDim.x + threadIdx.x;
    if (idx < BNZX) { hA[idx] = 0.0f; hB[idx] = 0.0f; }
    if (idx < NZX)  { float v = vp[idx] * DT; c2[idx] = v * v; }
}

// One time step: hn = 2*h1 - h2 + c2dt2 * lap(h1); inject source; write in-place
// into h2 (h2 is only ever read at the center cell, so this is race-free).
// The last block gathers receivers from h1 (= hn of step t-1).
__global__ void wave_step(const float* __restrict__ h1, float* __restrict__ h2dst,
                          const float* __restrict__ c2, const float* __restrict__ x,
                          const int* __restrict__ src_y, const int* __restrict__ src_x,
                          const int* __restrict__ rec_y, const int* __restrict__ rec_x,
                          float* __restrict__ y, int t) {
    int gb = blockIdx.x;
    if (gb == BNZX / 256) {
        // gather block: record receivers for step t-1 (h1 holds that hn, post-injection)
        if (t > 0) {
            for (int g = threadIdx.x; g < BB * NREC; g += 256) {
                int b = g >> 7, r = g & 127;
                y[(size_t)(t - 1) * (BB * NREC) + g] =
                    h1[b * NZX + rec_y[r] * NX + rec_x[r]];
            }
        }
        return;
    }
    int idx = gb * 256 + threadIdx.x;
    int b   = idx / NZX;
    int rem = idx - b * NZX;
    int z   = rem / NX;
    int xx  = rem - z * NX;

    float h1c = h1[idx];
    float lap = 0.0f;
    if (z > 0 && z < NZ - 1 && xx > 0 && xx < NX - 1) {
        lap = (h1[idx - NX] + h1[idx + NX] + h1[idx - 1] + h1[idx + 1] - 4.0f * h1c)
              * INV_DH2;
    }
    float hn = 2.0f * h1c - h2dst[idx] + c2[rem] * lap;
    if (z == src_y[b] && xx == src_x[b]) hn += x[b * NT + t];
    h2dst[idx] = hn;
}

// Record receivers for the final step.
__global__ void wave_final_gather(const float* __restrict__ h,
                                  const int* __restrict__ rec_y,
                                  const int* __restrict__ rec_x,
                                  float* __restrict__ y) {
    int g = blockIdx.x * blockDim.x + threadIdx.x;
    if (g < BB * NREC) {
        int b = g >> 7, r = g & 127;
        y[(size_t)(NT - 1) * (BB * NREC) + g] =
            h[b * NZX + rec_y[r] * NX + rec_x[r]];
    }
}

extern "C" void kernel_launch(void* const* d_in, const int* in_sizes, int n_in,
                              void* d_out, int out_size, void* d_ws, size_t ws_size,
                              hipStream_t stream) {
    const float* x     = (const float*)d_in[0];
    const float* vp    = (const float*)d_in[1];
    const int*   src_y = (const int*)d_in[2];
    const int*   src_x = (const int*)d_in[3];
    const int*   rec_y = (const int*)d_in[4];
    const int*   rec_x = (const int*)d_in[5];
    float* y = (float*)d_out;

    float* hA = (float*)d_ws;            // BNZX floats
    float* hB = hA + BNZX;               // BNZX floats
    float* c2 = hB + BNZX;               // NZX floats

    wave_init<<<(BNZX + 255) / 256, 256, 0, stream>>>(vp, hA, hB, c2);

    float* bufs[2] = { hA, hB };
    for (int t = 0; t < NT; ++t) {
        // h1 = bufs[t&1], write hn in-place over h2 = bufs[(t+1)&1]
        wave_step<<<BNZX / 256 + 1, 256, 0, stream>>>(
            bufs[t & 1], bufs[(t + 1) & 1], c2, x, src_y, src_x, rec_y, rec_x, y, t);
    }
    // after step NT-1, hn lives in bufs[NT & 1] == bufs[0]
    wave_final_gather<<<2, 256, 0, stream>>>(bufs[0], rec_y, rec_x, y);
}